// Round 4
// baseline (332.469 us; speedup 1.0000x reference)
//
#include <hip/hip_runtime.h>
#include <hip/hip_cooperative_groups.h>

namespace cg = cooperative_groups;

// bpd_cuda: super-BPD boundary angle diff, 512x512. R4: single cooperative kernel.
//  Phase A : per 32x32 tile (LDS): compute pf (angle-bin parent), LDS union-find
//            over intra-tile edges, publish depth-1 global par.
//  Phase B : cross-tile unions only, with par[n]-dedup (tile-roots repeat).
//  Phase C1: full compression (atomicMin par[t] <- root == min-index label), c3 = pf^3.
//  Phase C2: out[i,j,{right,down}] = wrapped |ang[c3] - ang[c3 of nbr]| where labels differ.
// All par mutations are atomicMin -> monotone decreasing; skip-if-rep-equal is safe
// because rep equality at any time implies connectivity (monotone property).
// Converged root per component == min flat index == FastSV converged label.

static constexpr double PI_D = 3.14159265;
#define NB 256
#define NT 256

__device__ __constant__ int c_DH[8] = {1, 1, 0, -1, -1, -1, 0, 1};
__device__ __constant__ int c_DW[8] = {0, 1, 1, 1, 0, -1, -1, -1};

// static fallback scratch (3 int arrays for N<=512*512) in case ws_size is small
__device__ int g_fb[3 * 262144];

// find with path-halving; all writes via atomicMin (monotone, benign races)
__device__ __forceinline__ int uf_find(int x, int* par) {
    while (true) {
        int p = par[x];
        if (p == x) return x;
        int gp = par[p];
        if (gp == p) return p;
        atomicMin(&par[x], gp);
        x = gp;
    }
}

// lock-free min-hooking link of two reps; returns merged rep.
// On CAS-miss (old != rv) the clobbered edge rv->old is repaired by continuing
// with find(old) (ECL-CC style) — same logic that passed R1-R3.
__device__ __forceinline__ int uf_link(int ru, int rv, int* par) {
    while (ru != rv) {
        if (ru > rv) { int t2 = ru; ru = rv; rv = t2; }   // ru < rv
        int old = atomicMin(&par[rv], ru);
        if (old == rv) break;          // rv was a root: linked
        rv = uf_find(old, par);        // repair: merge old's comp too
        ru = uf_find(ru, par);
    }
    return ru;
}

__device__ __forceinline__ void uf_unite(int u, int v, int* par) {
    uf_link(uf_find(u, par), uf_find(v, par), par);
}

// per-pixel parent from the angle field (bit-exact vs the JAX f32 reference)
__device__ __forceinline__ int parent_of(const float* __restrict__ ang,
                                         int t, int i, int j, int H, int W, float thr) {
    const float a = ang[t];
    const float a8 = (float)(PI_D / 8.0);
    const float a4 = (float)(PI_D / 4.0);
    float posf = rintf((a + a8) / a4);        // jnp.round == round-half-even == rintf
    if (posf >= 8.0f) posf -= 8.0f;
    const int pos = (int)posf;
    const int nh = i + c_DH[pos];
    const int nw = j + c_DW[pos];
    const bool inb = (nh >= 0) & (nh < H) & (nw >= 0) & (nw < W);
    const int nhc = min(max(nh, 0), H - 1);
    const int nwc = min(max(nw, 0), W - 1);
    float ad = fabsf(a - ang[nhc * W + nwc]);
    const float twopi = (float)(2.0 * PI_D);
    ad = fminf(ad, twopi - ad);
    const bool is_root = (!inb) || (ad > thr);
    return is_root ? t : (nhc * W + nwc);
}

__global__ void __launch_bounds__(NT, 1)
k_all(const float* __restrict__ ang,
      const int* __restrict__ hp, const int* __restrict__ wp,
      const int* __restrict__ tap, int N,
      int* __restrict__ pf, int* par, int* __restrict__ c3,
      float* __restrict__ out) {
    const int H = hp[0], W = wp[0];
    const float thr = (float)((double)tap[0] * PI_D / 180.0);
    const int tpr = (W + 31) >> 5;
    const int ntiles = tpr * ((H + 31) >> 5);
    __shared__ int lpar[1024];
    __shared__ int lpf[1024];

    // ---------- Phase A: per-tile CC in LDS ----------
    for (int tile = blockIdx.x; tile < ntiles; tile += gridDim.x) {
        const int ti0 = (tile / tpr) << 5, tj0 = (tile % tpr) << 5;
        for (int lp = threadIdx.x; lp < 1024; lp += NT) {
            lpar[lp] = lp;
            const int i = ti0 + (lp >> 5), j = tj0 + (lp & 31);
            int p = -1;
            if (i < H && j < W) {
                const int g = i * W + j;
                p = parent_of(ang, g, i, j, H, W, thr);
                pf[g] = p;
            }
            lpf[lp] = p;
        }
        __syncthreads();
        for (int lp = threadIdx.x; lp < 1024; lp += NT) {
            const int li = lp >> 5, lj = lp & 31;
            const int i = ti0 + li, j = tj0 + lj;
            if (i >= H || j >= W) continue;
            const int g = i * W + j;
            const int p = lpf[lp];
            if (p != g) {
                const int pi = p / W, pj = p - pi * W;
                const int pli = pi - ti0, plj = pj - tj0;
                if (((unsigned)pli < 32u) && ((unsigned)plj < 32u))
                    uf_unite(lp, (pli << 5) + plj, lpar);
            } else {
                for (int dh = 0; dh <= 2; ++dh) {
                    const int nh = i + dh;
                    if (nh > H - 2) break;
                    const int nli = li + dh;
                    if (nli >= 32) break;
                    for (int dw = -3; dw <= 2; ++dw) {
                        if (dh == 0 && dw == 0) continue;
                        const int nw = j + dw;
                        if ((unsigned)nw > (unsigned)(W - 2)) continue;
                        const int nlj = lj + dw;
                        if ((unsigned)nlj > 31u) continue;
                        const int nlp = (nli << 5) + nlj;
                        if (lpf[nlp] == nh * W + nw) uf_unite(lp, nlp, lpar);
                    }
                }
            }
        }
        __syncthreads();
        for (int lp = threadIdx.x; lp < 1024; lp += NT) {
            const int i = ti0 + (lp >> 5), j = tj0 + (lp & 31);
            if (i >= H || j >= W) continue;
            const int lr = uf_find(lp, lpar);
            par[i * W + j] = (ti0 + (lr >> 5)) * W + (tj0 + (lr & 31));
        }
        __syncthreads();   // LDS reuse across grid-stride iterations
    }
    cg::this_grid().sync();

    // ---------- Phase B: cross-tile unions ----------
    const int nth = gridDim.x * NT;
    const int t0 = blockIdx.x * NT + threadIdx.x;
    for (int t = t0; t < N; t += nth) {
        const int i = t / W, j = t - i * W;
        const int p = pf[t];
        if (p != t) {
            const int pi = p / W, pj = p - pi * W;
            if (((pi ^ i) | (pj ^ j)) & ~31)          // parent in another tile
                uf_unite(t, p, par);
            continue;                                  // non-roots have no window edges
        }
        const int li = i & 31, lj = j & 31;
        if (li < 30 && lj >= 3 && lj < 30) continue;   // no window edge can cross
        int ru = -1, lastpn = -1;
        for (int dh = 0; dh <= 2; ++dh) {
            const int nh = i + dh;
            if (nh > H - 2) break;
            for (int dw = -3; dw <= 2; ++dw) {
                if (dh == 0 && dw == 0) continue;
                const int nw = j + dw;
                if ((unsigned)nw > (unsigned)(W - 2)) continue;
                if ((((nh ^ i) | (nw ^ j)) & ~31) == 0) continue;  // same tile: done in A
                const int n = nh * W + nw;
                if (pf[n] != n) continue;              // window edges need both roots
                const int pn = par[n];
                if (pn == lastpn) continue;            // same tile-root as last: connected
                lastpn = pn;
                const int rv = uf_find(pn, par);
                if (ru == -1) ru = uf_find(t, par);
                if (rv == ru) continue;
                ru = uf_link(ru, rv, par);
            }
        }
    }
    cg::this_grid().sync();

    // ---------- Phase C1: compress labels into par; c3 = pf^3 ----------
    for (int t = t0; t < N; t += nth) {
        const int r = uf_find(t, par);
        atomicMin(&par[t], r);         // monotone: par[t] == final root at next sync
        int p = pf[t];
        p = pf[p];
        c3[t] = pf[p];
    }
    cg::this_grid().sync();

    // ---------- Phase C2: output ----------
    const float twopi = (float)(2.0 * PI_D);
    for (int t = t0; t < N; t += nth) {
        const int i = t / W, j = t - i * W;
        const int l = par[t];
        const float ac = ang[c3[t]];
        float r0 = 0.0f, r1 = 0.0f;
        if (j + 1 < W && par[t + 1] != l) {
            float ad = fabsf(ac - ang[c3[t + 1]]);
            r0 = fminf(ad, twopi - ad);
        }
        if (i + 1 < H && par[t + W] != l) {
            float ad = fabsf(ac - ang[c3[t + W]]);
            r1 = fminf(ad, twopi - ad);
        }
        reinterpret_cast<float2*>(out)[t] = make_float2(r0, r1);
    }
}

extern "C" void kernel_launch(void* const* d_in, const int* in_sizes, int n_in,
                              void* d_out, int out_size, void* d_ws, size_t ws_size,
                              hipStream_t stream) {
    const float* ang = (const float*)d_in[0];
    const int* hp  = (const int*)d_in[1];
    const int* wp  = (const int*)d_in[2];
    const int* tap = (const int*)d_in[3];
    int N = in_sizes[0];

    int* base = (int*)d_ws;
    if (ws_size < (size_t)3 * (size_t)N * sizeof(int) && N <= 262144) {
        void* p = nullptr;
        hipGetSymbolAddress(&p, HIP_SYMBOL(g_fb));   // host-side query; capture-safe
        base = (int*)p;
    }
    int* pf  = base;
    int* par = base + N;
    int* c3  = base + 2 * N;
    float* op = (float*)d_out;

    void* kargs[] = {(void*)&ang, (void*)&hp, (void*)&wp, (void*)&tap,
                     (void*)&N, (void*)&pf, (void*)&par, (void*)&c3, (void*)&op};
    hipLaunchCooperativeKernel((const void*)k_all, dim3(NB), dim3(NT), kargs, 0, stream);
}

// Round 5
// 169.458 us; speedup vs baseline: 1.9620x; 1.9620x over previous
//
#include <hip/hip_runtime.h>

// bpd_cuda: super-BPD boundary angle diff, 512x512. R5: split kernels, lean atomics.
//  k_local   : per 32x32 tile (one block): compute pf inline, LDS union-find over
//              intra-tile edges, publish depth-1 global par, AND compute c3=pf^3 in
//              LDS for interior pixels (li,lj in [3,28] -> 3-hop chase stays in-tile).
//  k_global  : cross-tile unions only. Read-only finds (no compression RMWs);
//              correctness via atomicMin return-value repair (monotone par).
//  k_flatten : par[t] = final root (plain store; unions done); c3 for band pixels.
//  k_output  : wrapped |ang[c3]-ang[c3 of nbr]| for right/down where labels differ.
// Converged root per component == min flat index == FastSV converged label.

static constexpr double PI_D = 3.14159265;

__device__ __constant__ int c_DH[8] = {1, 1, 0, -1, -1, -1, 0, 1};
__device__ __constant__ int c_DW[8] = {0, 1, 1, 1, 0, -1, -1, -1};

// static fallback scratch (3 int arrays for N<=512*512) in case ws_size is small
__device__ int g_fb[3 * 262144];

// ---- LDS union-find (atomicMin path-halving; cheap on-CU atomics) ----
__device__ __forceinline__ int uf_find_lds(int x, int* par) {
    while (true) {
        int p = par[x];
        if (p == x) return x;
        int gp = par[p];
        if (gp == p) return p;
        atomicMin(&par[x], gp);
        x = gp;
    }
}
__device__ __forceinline__ void uf_unite_lds(int u, int v, int* par) {
    int ru = uf_find_lds(u, par);
    int rv = uf_find_lds(v, par);
    while (ru != rv) {
        if (ru > rv) { int t2 = ru; ru = rv; rv = t2; }
        int old = atomicMin(&par[rv], ru);
        if (old == rv) break;
        rv = uf_find_lds(old, par);
        ru = uf_find_lds(ru, par);
    }
}

// ---- global union-find: read-only walks, RMW only on hooks ----
__device__ __forceinline__ int find_ro(int x, const int* par) {
    int p = par[x];
    while (p != x) { x = p; p = par[x]; }
    return x;   // possibly stale-root; repaired by link's RMW return value
}
__device__ __forceinline__ int uf_link(int ru, int rv, int* par) {
    while (ru != rv) {
        if (ru > rv) { int t2 = ru; ru = rv; rv = t2; }   // ru < rv
        int old = atomicMin(&par[rv], ru);
        if (old == rv) break;          // rv really was a root: linked
        rv = find_ro(old, par);        // rv was already hooked; merge that comp too
        ru = find_ro(ru, par);
    }
    return ru;
}
__device__ __forceinline__ void uf_unite(int u, int v, int* par) {
    uf_link(find_ro(u, par), find_ro(v, par), par);
}

// per-pixel parent from the angle field (bit-exact vs the JAX f32 reference)
__device__ __forceinline__ int parent_of(const float* __restrict__ ang,
                                         int t, int i, int j, int H, int W, float thr) {
    const float a = ang[t];
    const float a8 = (float)(PI_D / 8.0);
    const float a4 = (float)(PI_D / 4.0);
    float posf = rintf((a + a8) / a4);        // jnp.round == round-half-even == rintf
    if (posf >= 8.0f) posf -= 8.0f;
    const int pos = (int)posf;
    const int nh = i + c_DH[pos];
    const int nw = j + c_DW[pos];
    const bool inb = (nh >= 0) & (nh < H) & (nw >= 0) & (nw < W);
    const int nhc = min(max(nh, 0), H - 1);
    const int nwc = min(max(nw, 0), W - 1);
    float ad = fabsf(a - ang[nhc * W + nwc]);
    const float twopi = (float)(2.0 * PI_D);
    ad = fminf(ad, twopi - ad);
    const bool is_root = (!inb) || (ad > thr);
    return is_root ? t : (nhc * W + nwc);
}

// one 32x32 tile per block: pf inline, LDS CC, publish par, interior c3
__global__ void k_local(const float* __restrict__ ang,
                        const int* __restrict__ hp, const int* __restrict__ wp,
                        const int* __restrict__ tap, int N,
                        int* __restrict__ pf, int* __restrict__ par,
                        int* __restrict__ c3) {
    const int H = hp[0], W = wp[0];
    const float thr = (float)((double)tap[0] * PI_D / 180.0);
    const int tpr = (W + 31) >> 5;
    const int ntiles = tpr * ((H + 31) >> 5);
    __shared__ int lpar[1024];
    __shared__ int lpf[1024];
    for (int tile = blockIdx.x; tile < ntiles; tile += gridDim.x) {
        const int ti0 = (tile / tpr) << 5, tj0 = (tile % tpr) << 5;
        for (int lp = threadIdx.x; lp < 1024; lp += blockDim.x) {
            lpar[lp] = lp;
            const int i = ti0 + (lp >> 5), j = tj0 + (lp & 31);
            int p = -1;
            if (i < H && j < W) {
                const int g = i * W + j;
                p = parent_of(ang, g, i, j, H, W, thr);
                pf[g] = p;
            }
            lpf[lp] = p;
        }
        __syncthreads();
        for (int lp = threadIdx.x; lp < 1024; lp += blockDim.x) {
            const int li = lp >> 5, lj = lp & 31;
            const int i = ti0 + li, j = tj0 + lj;
            if (i >= H || j >= W) continue;
            const int g = i * W + j;
            const int p = lpf[lp];
            if (p != g) {
                const int pi = p / W, pj = p - pi * W;
                const int pli = pi - ti0, plj = pj - tj0;
                if (((unsigned)pli < 32u) && ((unsigned)plj < 32u))
                    uf_unite_lds(lp, (pli << 5) + plj, lpar);
            } else {
                for (int dh = 0; dh <= 2; ++dh) {
                    const int nh = i + dh;
                    if (nh > H - 2) break;
                    const int nli = li + dh;
                    if (nli >= 32) break;
                    for (int dw = -3; dw <= 2; ++dw) {
                        if (dh == 0 && dw == 0) continue;
                        const int nw = j + dw;
                        if ((unsigned)nw > (unsigned)(W - 2)) continue;
                        const int nlj = lj + dw;
                        if ((unsigned)nlj > 31u) continue;
                        const int nlp = (nli << 5) + nlj;
                        if (lpf[nlp] == nh * W + nw) uf_unite_lds(lp, nlp, lpar);
                    }
                }
            }
        }
        __syncthreads();
        for (int lp = threadIdx.x; lp < 1024; lp += blockDim.x) {
            const int li = lp >> 5, lj = lp & 31;
            const int i = ti0 + li, j = tj0 + lj;
            if (i >= H || j >= W) continue;
            const int lr = uf_find_lds(lp, lpar);
            par[i * W + j] = (ti0 + (lr >> 5)) * W + (tj0 + (lr & 31));
            // interior pixels: 3-hop pf chase provably stays in-tile -> resolve in LDS
            if (li >= 3 && li <= 28 && lj >= 3 && lj <= 28) {
                const int p1 = lpf[lp];
                const int r1 = p1 / W;
                const int l1 = ((r1 - ti0) << 5) + (p1 - r1 * W - tj0);
                const int p2 = lpf[l1];
                const int r2 = p2 / W;
                const int l2 = ((r2 - ti0) << 5) + (p2 - r2 * W - tj0);
                c3[i * W + j] = lpf[l2];
            }
        }
        __syncthreads();   // LDS reuse across grid-stride iterations
    }
}

// cross-tile unions only (read-only finds, dedup via tile-root value)
__global__ void k_global(const int* __restrict__ pf,
                         const int* __restrict__ hp, const int* __restrict__ wp,
                         int N, int* par) {
    int t = blockIdx.x * blockDim.x + threadIdx.x;
    if (t >= N) return;
    const int H = hp[0], W = wp[0];
    const int i = t / W, j = t - i * W;
    const int p = pf[t];
    if (p != t) {
        const int pi = p / W, pj = p - pi * W;
        if (((pi ^ i) | (pj ^ j)) & ~31)           // parent in another tile
            uf_unite(t, p, par);
        return;                                    // non-roots have no window edges
    }
    const int li = i & 31, lj = j & 31;
    if (li < 30 && lj >= 3 && lj < 30) return;     // no window edge can cross a tile
    int ru = -1, lastpn = -1;
    for (int dh = 0; dh <= 2; ++dh) {
        const int nh = i + dh;
        if (nh > H - 2) break;
        for (int dw = -3; dw <= 2; ++dw) {
            if (dh == 0 && dw == 0) continue;
            const int nw = j + dw;
            if ((unsigned)nw > (unsigned)(W - 2)) continue;
            if ((((nh ^ i) | (nw ^ j)) & ~31) == 0) continue;   // same tile: done locally
            const int n = nh * W + nw;
            if (pf[n] != n) continue;              // window edges need both roots
            const int pn = par[n];                 // n's tile-root (depth-1)
            if (pn == lastpn) continue;            // same tile-root as last: connected
            lastpn = pn;
            const int rv = find_ro(pn, par);
            if (ru == -1) ru = find_ro(t, par);
            if (rv == ru) continue;
            ru = uf_link(ru, rv, par);
        }
    }
}

// par[t] <- final root (plain store, unions complete); c3 for band pixels
__global__ void k_flatten(const int* __restrict__ pf,
                          const int* __restrict__ hp, const int* __restrict__ wp,
                          int N, int* par, int* __restrict__ c3) {
    int t = blockIdx.x * blockDim.x + threadIdx.x;
    if (t >= N) return;
    const int W = wp[0];
    const int r = find_ro(t, par);
    par[t] = r;                                    // reuse par as the label array
    const int i = t / W, j = t - i * W;
    const int li = i & 31, lj = j & 31;
    if (!(li >= 3 && li <= 28 && lj >= 3 && lj <= 28)) {
        int p = pf[t];
        p = pf[p];
        c3[t] = pf[p];
    }
}

__global__ void k_output(const float* __restrict__ ang,
                         const int* __restrict__ par, const int* __restrict__ c3,
                         const int* __restrict__ hp, const int* __restrict__ wp,
                         int N, float* __restrict__ out) {
    int t = blockIdx.x * blockDim.x + threadIdx.x;
    if (t >= N) return;
    const int H = hp[0], W = wp[0];
    const int i = t / W, j = t - i * W;
    const float twopi = (float)(2.0 * PI_D);
    const int l = par[t];
    const float ac = ang[c3[t]];
    float r0 = 0.0f, r1 = 0.0f;
    if (j + 1 < W && par[t + 1] != l) {
        float ad = fabsf(ac - ang[c3[t + 1]]);
        r0 = fminf(ad, twopi - ad);
    }
    if (i + 1 < H && par[t + W] != l) {
        float ad = fabsf(ac - ang[c3[t + W]]);
        r1 = fminf(ad, twopi - ad);
    }
    reinterpret_cast<float2*>(out)[t] = make_float2(r0, r1);
}

extern "C" void kernel_launch(void* const* d_in, const int* in_sizes, int n_in,
                              void* d_out, int out_size, void* d_ws, size_t ws_size,
                              hipStream_t stream) {
    const float* ang = (const float*)d_in[0];
    const int* hp  = (const int*)d_in[1];
    const int* wp  = (const int*)d_in[2];
    const int* tap = (const int*)d_in[3];
    const int N = in_sizes[0];

    int* base = (int*)d_ws;
    if (ws_size < (size_t)3 * (size_t)N * sizeof(int) && N <= 262144) {
        void* p = nullptr;
        hipGetSymbolAddress(&p, HIP_SYMBOL(g_fb));   // host-side query; capture-safe
        base = (int*)p;
    }
    int* pf  = base;
    int* par = base + N;
    int* c3  = base + 2 * N;

    const int threads = 256;
    const int blocks = (N + threads - 1) / threads;
    const int ntiles = ((512 + 31) / 32) * ((512 + 31) / 32);   // grid-stride handles any H,W
    k_local  <<<min(ntiles, 256), threads, 0, stream>>>(ang, hp, wp, tap, N, pf, par, c3);
    k_global <<<blocks, threads, 0, stream>>>(pf, hp, wp, N, par);
    k_flatten<<<blocks, threads, 0, stream>>>(pf, hp, wp, N, par, c3);
    k_output <<<blocks, threads, 0, stream>>>(ang, par, c3, hp, wp, N, (float*)d_out);
}

// Round 6
// 151.862 us; speedup vs baseline: 2.1893x; 1.1159x over previous
//
#include <hip/hip_runtime.h>

// bpd_cuda: super-BPD boundary angle diff, 512x512. R6.
//  k_local  : per 32x32 tile: pf inline, LDS union-find (intra-tile edges),
//             publish depth-1 par, interior c3 = pf^3, append local roots to wlist.
//  k_global : cross-tile unions, COMPACT launch (only the 241 border-band pixels
//             per tile that can have a cross-tile edge). Read-only finds; RMW only
//             on hooks (atomicMin return-value repair, ECL-CC style).
//  k_roots  : compress only the ~local-root worklist: par[r] = find(r).
//             After this, label(t) == par[par[t]] (two flat loads).
//  k_output : labels inline via par[par[.]]; c3 from array (interior) or pf^3 (band).
// All par mutations monotone-decreasing; converged root == min index == FastSV label.

static constexpr double PI_D = 3.14159265;

__device__ __constant__ int c_DH[8] = {1, 1, 0, -1, -1, -1, 0, 1};
__device__ __constant__ int c_DW[8] = {0, 1, 1, 1, 0, -1, -1, -1};

// static fallback scratch: pf, par, c3, wlist (N each) + wcount, for N<=262144
__device__ int g_fb[4 * 262144 + 64];

// ---- LDS union-find (atomicMin path-halving; cheap on-CU atomics) ----
__device__ __forceinline__ int uf_find_lds(int x, int* par) {
    while (true) {
        int p = par[x];
        if (p == x) return x;
        int gp = par[p];
        if (gp == p) return p;
        atomicMin(&par[x], gp);
        x = gp;
    }
}
__device__ __forceinline__ void uf_unite_lds(int u, int v, int* par) {
    int ru = uf_find_lds(u, par);
    int rv = uf_find_lds(v, par);
    while (ru != rv) {
        if (ru > rv) { int t2 = ru; ru = rv; rv = t2; }
        int old = atomicMin(&par[rv], ru);
        if (old == rv) break;
        rv = uf_find_lds(old, par);
        ru = uf_find_lds(ru, par);
    }
}

// ---- global union-find: read-only walks, RMW only on hooks ----
__device__ __forceinline__ int find_ro(int x, const int* par) {
    int p = par[x];
    while (p != x) { x = p; p = par[x]; }
    return x;   // possibly stale-root; repaired by link's RMW return value
}
__device__ __forceinline__ int uf_link(int ru, int rv, int* par) {
    while (ru != rv) {
        if (ru > rv) { int t2 = ru; ru = rv; rv = t2; }   // ru < rv
        int old = atomicMin(&par[rv], ru);
        if (old == rv) break;          // rv really was a root: linked
        rv = find_ro(old, par);        // rv was already hooked; merge that comp too
        ru = find_ro(ru, par);
    }
    return ru;
}
__device__ __forceinline__ void uf_unite(int u, int v, int* par) {
    uf_link(find_ro(u, par), find_ro(v, par), par);
}

// per-pixel parent from the angle field (bit-exact vs the JAX f32 reference)
__device__ __forceinline__ int parent_of(const float* __restrict__ ang,
                                         int t, int i, int j, int H, int W, float thr) {
    const float a = ang[t];
    const float a8 = (float)(PI_D / 8.0);
    const float a4 = (float)(PI_D / 4.0);
    float posf = rintf((a + a8) / a4);        // jnp.round == round-half-even == rintf
    if (posf >= 8.0f) posf -= 8.0f;
    const int pos = (int)posf;
    const int nh = i + c_DH[pos];
    const int nw = j + c_DW[pos];
    const bool inb = (nh >= 0) & (nh < H) & (nw >= 0) & (nw < W);
    const int nhc = min(max(nh, 0), H - 1);
    const int nwc = min(max(nw, 0), W - 1);
    float ad = fabsf(a - ang[nhc * W + nwc]);
    const float twopi = (float)(2.0 * PI_D);
    ad = fminf(ad, twopi - ad);
    const bool is_root = (!inb) || (ad > thr);
    return is_root ? t : (nhc * W + nwc);
}

// one 32x32 tile per block iteration: pf inline, LDS CC, publish, interior c3, wlist
__global__ void k_local(const float* __restrict__ ang,
                        const int* __restrict__ hp, const int* __restrict__ wp,
                        const int* __restrict__ tap, int N,
                        int* __restrict__ pf, int* __restrict__ par,
                        int* __restrict__ c3,
                        int* __restrict__ wlist, int* __restrict__ wcount) {
    const int H = hp[0], W = wp[0];
    const float thr = (float)((double)tap[0] * PI_D / 180.0);
    const int tpr = (W + 31) >> 5;
    const int ntiles = tpr * ((H + 31) >> 5);
    __shared__ int lpar[1024];
    __shared__ int lpf[1024];
    for (int tile = blockIdx.x; tile < ntiles; tile += gridDim.x) {
        const int ti0 = (tile / tpr) << 5, tj0 = (tile % tpr) << 5;
        for (int lp = threadIdx.x; lp < 1024; lp += blockDim.x) {
            lpar[lp] = lp;
            const int i = ti0 + (lp >> 5), j = tj0 + (lp & 31);
            int p = -1;
            if (i < H && j < W) {
                const int g = i * W + j;
                p = parent_of(ang, g, i, j, H, W, thr);
                pf[g] = p;
            }
            lpf[lp] = p;
        }
        __syncthreads();
        for (int lp = threadIdx.x; lp < 1024; lp += blockDim.x) {
            const int li = lp >> 5, lj = lp & 31;
            const int i = ti0 + li, j = tj0 + lj;
            if (i >= H || j >= W) continue;
            const int g = i * W + j;
            const int p = lpf[lp];
            if (p != g) {
                const int pi = p / W, pj = p - pi * W;
                const int pli = pi - ti0, plj = pj - tj0;
                if (((unsigned)pli < 32u) && ((unsigned)plj < 32u))
                    uf_unite_lds(lp, (pli << 5) + plj, lpar);
            } else {
                for (int dh = 0; dh <= 2; ++dh) {
                    const int nh = i + dh;
                    if (nh > H - 2) break;
                    const int nli = li + dh;
                    if (nli >= 32) break;
                    for (int dw = -3; dw <= 2; ++dw) {
                        if (dh == 0 && dw == 0) continue;
                        const int nw = j + dw;
                        if ((unsigned)nw > (unsigned)(W - 2)) continue;
                        const int nlj = lj + dw;
                        if ((unsigned)nlj > 31u) continue;
                        const int nlp = (nli << 5) + nlj;
                        if (lpf[nlp] == nh * W + nw) uf_unite_lds(lp, nlp, lpar);
                    }
                }
            }
        }
        __syncthreads();
        for (int lp = threadIdx.x; lp < 1024; lp += blockDim.x) {
            const int li = lp >> 5, lj = lp & 31;
            const int i = ti0 + li, j = tj0 + lj;
            if (i >= H || j >= W) continue;
            const int g = i * W + j;
            const int lr = uf_find_lds(lp, lpar);
            par[g] = (ti0 + (lr >> 5)) * W + (tj0 + (lr & 31));
            if (lr == lp) wlist[atomicAdd(wcount, 1)] = g;   // local-component root
            // interior pixels: 3-hop pf chase provably stays in-tile -> resolve in LDS
            if (li >= 3 && li <= 28 && lj >= 3 && lj <= 28) {
                const int p1 = lpf[lp];
                const int r1 = p1 / W;
                const int l1 = ((r1 - ti0) << 5) + (p1 - r1 * W - tj0);
                const int p2 = lpf[l1];
                const int r2 = p2 / W;
                const int l2 = ((r2 - ti0) << 5) + (p2 - r2 * W - tj0);
                c3[g] = lpf[l2];
            }
        }
        __syncthreads();   // LDS reuse across grid-stride iterations
    }
}

// cross-tile unions, compact: only the 241 band pixels per tile can have one
__global__ void k_global(const int* __restrict__ pf,
                         const int* __restrict__ hp, const int* __restrict__ wp,
                         int N, int* par) {
    const int H = hp[0], W = wp[0];
    const int tpr = (W + 31) >> 5;
    const int ntiles = tpr * ((H + 31) >> 5);
    const int tidx = threadIdx.x;
    if (tidx >= 241) return;
    int li, lj;
    if (tidx < 96) {                     // rows {0,30,31}, all 32 cols
        const int r = tidx >> 5;
        li = (r == 0) ? 0 : 29 + r;
        lj = tidx & 31;
    } else {                             // rows 1..29, cols {0,1,2,30,31}
        const int u = tidx - 96;
        li = 1 + u / 5;
        const int c = u % 5;
        lj = (c < 3) ? c : 27 + c;
    }
    for (int tile = blockIdx.x; tile < ntiles; tile += gridDim.x) {
        const int i = ((tile / tpr) << 5) + li;
        const int j = ((tile % tpr) << 5) + lj;
        if (i >= H || j >= W) continue;
        const int t = i * W + j;
        const int p = pf[t];
        if (p != t) {
            const int pi = p / W, pj = p - pi * W;
            if (((pi ^ i) | (pj ^ j)) & ~31)          // parent in another tile
                uf_unite(t, p, par);
            continue;                                 // non-roots have no window edges
        }
        if (li < 30 && lj >= 3 && lj < 30) continue;  // perimeter-only pixel: parent case only
        int ru = -1, lastpn = -1;
        for (int dh = 0; dh <= 2; ++dh) {
            const int nh = i + dh;
            if (nh > H - 2) break;
            for (int dw = -3; dw <= 2; ++dw) {
                if (dh == 0 && dw == 0) continue;
                const int nw = j + dw;
                if ((unsigned)nw > (unsigned)(W - 2)) continue;
                if ((((nh ^ i) | (nw ^ j)) & ~31) == 0) continue;   // same tile
                const int n = nh * W + nw;
                if (pf[n] != n) continue;             // window edges need both roots
                const int pn = par[n];                // n's tile-local root (depth-1)
                if (pn == lastpn) continue;           // same local root: already connected
                lastpn = pn;
                const int rv = find_ro(pn, par);
                if (ru == -1) ru = find_ro(t, par);
                if (rv == ru) continue;
                ru = uf_link(ru, rv, par);
            }
        }
    }
}

// compress only the local-component roots; afterwards label(t) == par[par[t]]
__global__ void k_roots(const int* __restrict__ wlist, const int* __restrict__ wcount,
                        int* par) {
    const int n = *wcount;
    for (int k = blockIdx.x * blockDim.x + threadIdx.x; k < n;
         k += gridDim.x * blockDim.x) {
        const int r = wlist[k];
        par[r] = find_ro(r, par);   // plain store of final value (unions complete)
    }
}

__global__ void k_output(const float* __restrict__ ang,
                         const int* __restrict__ par, const int* __restrict__ pf,
                         const int* __restrict__ c3,
                         const int* __restrict__ hp, const int* __restrict__ wp,
                         int N, float* __restrict__ out) {
    int t = blockIdx.x * blockDim.x + threadIdx.x;
    if (t >= N) return;
    const int H = hp[0], W = wp[0];
    const int i = t / W, j = t - i * W;
    const float twopi = (float)(2.0 * PI_D);
    const int l = par[par[t]];
    float r0 = 0.0f, r1 = 0.0f;
    bool need = false;
    int l1 = l, l2 = l;
    if (j + 1 < W) { l1 = par[par[t + 1]]; need |= (l1 != l); }
    if (i + 1 < H) { l2 = par[par[t + W]]; need |= (l2 != l); }
    if (need) {
        // c3 of x: interior (li,lj in [3,28]) -> array; band -> pf^3 inline
        auto c3v = [&](int x) {
            const int xi = x / W, xj = x - xi * W;
            const int xli = xi & 31, xlj = xj & 31;
            if (xli >= 3 && xli <= 28 && xlj >= 3 && xlj <= 28) return c3[x];
            int p = pf[x];
            p = pf[p];
            return pf[p];
        };
        const float ac = ang[c3v(t)];
        if (l1 != l) {
            float ad = fabsf(ac - ang[c3v(t + 1)]);
            r0 = fminf(ad, twopi - ad);
        }
        if (l2 != l) {
            float ad = fabsf(ac - ang[c3v(t + W)]);
            r1 = fminf(ad, twopi - ad);
        }
    }
    reinterpret_cast<float2*>(out)[t] = make_float2(r0, r1);
}

extern "C" void kernel_launch(void* const* d_in, const int* in_sizes, int n_in,
                              void* d_out, int out_size, void* d_ws, size_t ws_size,
                              hipStream_t stream) {
    const float* ang = (const float*)d_in[0];
    const int* hp  = (const int*)d_in[1];
    const int* wp  = (const int*)d_in[2];
    const int* tap = (const int*)d_in[3];
    const int N = in_sizes[0];

    int* base = (int*)d_ws;
    if (ws_size < ((size_t)4 * (size_t)N + 1) * sizeof(int) && N <= 262144) {
        void* p = nullptr;
        hipGetSymbolAddress(&p, HIP_SYMBOL(g_fb));   // host-side query; capture-safe
        base = (int*)p;
    }
    int* pf     = base;
    int* par    = base + N;
    int* c3     = base + 2 * N;
    int* wlist  = base + 3 * N;
    int* wcount = base + 4 * N;

    hipMemsetAsync(wcount, 0, sizeof(int), stream);   // ws is re-poisoned every call

    const int threads = 256;
    const int blocks = (N + threads - 1) / threads;
    k_local <<<256, 512, 0, stream>>>(ang, hp, wp, tap, N, pf, par, c3, wlist, wcount);
    k_global<<<256, 256, 0, stream>>>(pf, hp, wp, N, par);
    k_roots <<<64, 256, 0, stream>>>(wlist, wcount, par);
    k_output<<<blocks, threads, 0, stream>>>(ang, par, pf, c3, hp, wp, N, (float*)d_out);
}

// Round 7
// 137.858 us; speedup vs baseline: 2.4117x; 1.1016x over previous
//
#include <hip/hip_runtime.h>

// bpd_cuda: super-BPD boundary angle diff, 512x512. R7.
//  k_local  : one 32x32 tile per block, 1024 threads (1 px/thread): pf inline,
//             LDS union-find over intra-tile edges (dh=0 window dedup'd to
//             rightward d in {1,2,3}), publish depth-1 par, interior c3 = pf^3,
//             append tile-local roots to wlist.
//  k_global : cross-tile unions, compact band (270 px/tile), read-only finds,
//             RMW only on hooks, 2-deep tile-root history dedup.
//  k_roots  : compress only the local-root worklist -> label(t)==par[par[t]].
//  k_output : labels via par[par[.]]; c3 from array (interior) or pf^3 (band).
// Dedup'd horizontal edge set (proved equal to the reference's two-sided
// enumeration): pair {(i,j),(i,j+d)}, d in {1,2,3}, exists iff both endpoints
// roots AND i <= H-2 AND j+d <= W-1.
// All par mutations monotone-decreasing; converged root == min index == FastSV label.

static constexpr double PI_D = 3.14159265;

__device__ __constant__ int c_DH[8] = {1, 1, 0, -1, -1, -1, 0, 1};
__device__ __constant__ int c_DW[8] = {0, 1, 1, 1, 0, -1, -1, -1};

// static fallback scratch: pf, par, c3, wlist (N each) + wcount, for N<=262144
__device__ int g_fb[4 * 262144 + 64];

// ---- LDS union-find (atomicMin path-halving; cheap on-CU atomics) ----
__device__ __forceinline__ int uf_find_lds(int x, int* par) {
    while (true) {
        int p = par[x];
        if (p == x) return x;
        int gp = par[p];
        if (gp == p) return p;
        atomicMin(&par[x], gp);
        x = gp;
    }
}
__device__ __forceinline__ void uf_unite_lds(int u, int v, int* par) {
    int ru = uf_find_lds(u, par);
    int rv = uf_find_lds(v, par);
    while (ru != rv) {
        if (ru > rv) { int t2 = ru; ru = rv; rv = t2; }
        int old = atomicMin(&par[rv], ru);
        if (old == rv) break;
        rv = uf_find_lds(old, par);
        ru = uf_find_lds(ru, par);
    }
}

// ---- global union-find: read-only walks, RMW only on hooks ----
__device__ __forceinline__ int find_ro(int x, const int* par) {
    int p = par[x];
    while (p != x) { x = p; p = par[x]; }
    return x;   // possibly stale-root; repaired by link's RMW return value
}
__device__ __forceinline__ int uf_link(int ru, int rv, int* par) {
    while (ru != rv) {
        if (ru > rv) { int t2 = ru; ru = rv; rv = t2; }   // ru < rv
        int old = atomicMin(&par[rv], ru);
        if (old == rv) break;          // rv really was a root: linked
        rv = find_ro(old, par);        // rv was already hooked; merge that comp too
        ru = find_ro(ru, par);
    }
    return ru;
}
__device__ __forceinline__ void uf_unite(int u, int v, int* par) {
    uf_link(find_ro(u, par), find_ro(v, par), par);
}

// per-pixel parent from the angle field (bit-exact vs the JAX f32 reference)
__device__ __forceinline__ int parent_of(const float* __restrict__ ang,
                                         int t, int i, int j, int H, int W, float thr) {
    const float a = ang[t];
    const float a8 = (float)(PI_D / 8.0);
    const float a4 = (float)(PI_D / 4.0);
    float posf = rintf((a + a8) / a4);        // jnp.round == round-half-even == rintf
    if (posf >= 8.0f) posf -= 8.0f;
    const int pos = (int)posf;
    const int nh = i + c_DH[pos];
    const int nw = j + c_DW[pos];
    const bool inb = (nh >= 0) & (nh < H) & (nw >= 0) & (nw < W);
    const int nhc = min(max(nh, 0), H - 1);
    const int nwc = min(max(nw, 0), W - 1);
    float ad = fabsf(a - ang[nhc * W + nwc]);
    const float twopi = (float)(2.0 * PI_D);
    ad = fminf(ad, twopi - ad);
    const bool is_root = (!inb) || (ad > thr);
    return is_root ? t : (nhc * W + nwc);
}

// one 32x32 tile per block iteration, 1024 threads = 1 px each
__global__ void __launch_bounds__(1024)
k_local(const float* __restrict__ ang,
        const int* __restrict__ hp, const int* __restrict__ wp,
        const int* __restrict__ tap, int N,
        int* __restrict__ pf, int* __restrict__ par, int* __restrict__ c3,
        int* __restrict__ wlist, int* __restrict__ wcount) {
    const int H = hp[0], W = wp[0];
    const float thr = (float)((double)tap[0] * PI_D / 180.0);
    const int tpr = (W + 31) >> 5;
    const int ntiles = tpr * ((H + 31) >> 5);
    __shared__ int lpar[1024];
    __shared__ int lpf[1024];
    const int lp = threadIdx.x;
    const int li = lp >> 5, lj = lp & 31;
    for (int tile = blockIdx.x; tile < ntiles; tile += gridDim.x) {
        const int ti0 = (tile / tpr) << 5, tj0 = (tile % tpr) << 5;
        const int i = ti0 + li, j = tj0 + lj;
        const bool inpix = (i < H) && (j < W);
        const int g = i * W + j;
        lpar[lp] = lp;
        int p = -1;
        if (inpix) { p = parent_of(ang, g, i, j, H, W, thr); pf[g] = p; }
        lpf[lp] = p;
        __syncthreads();
        if (inpix) {
            if (p != g) {
                const int pi = p / W, pj = p - pi * W;
                const int pli = pi - ti0, plj = pj - tj0;
                if (((unsigned)pli < 32u) && ((unsigned)plj < 32u))
                    uf_unite_lds(lp, (pli << 5) + plj, lpar);
            } else if (i <= H - 2) {
                // dh=0 dedup'd: rightward d in {1,2,3}; cond: j+d<=W-1, both roots
                for (int d = 1; d <= 3; ++d) {
                    if (lj + d > 31) break;        // cross-tile: k_global
                    if (j + d > W - 1) break;
                    if (lpf[lp + d] == g + d) uf_unite_lds(lp, lp + d, lpar);
                }
                // dh in {1,2}: dw in {-3..2} (enumerated once, from top pixel)
                for (int dh = 1; dh <= 2; ++dh) {
                    const int nh = i + dh;
                    if (nh > H - 2) break;
                    const int nli = li + dh;
                    if (nli >= 32) break;
                    for (int dw = -3; dw <= 2; ++dw) {
                        const int nw = j + dw;
                        if ((unsigned)nw > (unsigned)(W - 2)) continue;
                        const int nlj = lj + dw;
                        if ((unsigned)nlj > 31u) continue;
                        const int nlp = (nli << 5) + nlj;
                        if (lpf[nlp] == nh * W + nw) uf_unite_lds(lp, nlp, lpar);
                    }
                }
            }
        }
        __syncthreads();
        if (inpix) {
            const int lr = uf_find_lds(lp, lpar);
            par[g] = (ti0 + (lr >> 5)) * W + (tj0 + (lr & 31));
            if (lr == lp) wlist[atomicAdd(wcount, 1)] = g;   // tile-local root
            // interior pixels: 3-hop pf chase provably stays in-tile
            if (li >= 3 && li <= 28 && lj >= 3 && lj <= 28) {
                const int p1 = lpf[lp];
                const int r1 = p1 / W;
                const int l1 = ((r1 - ti0) << 5) + (p1 - r1 * W - tj0);
                const int p2 = lpf[l1];
                const int r2 = p2 / W;
                const int l2 = ((r2 - ti0) << 5) + (p2 - r2 * W - tj0);
                c3[g] = lpf[l2];
            }
        }
        __syncthreads();   // LDS reuse across grid-stride iterations
    }
}

// cross-tile unions, compact band: rows {0,30,31} + cols {0,1,2,29,30,31} = 270/tile
__global__ void k_global(const int* __restrict__ pf,
                         const int* __restrict__ hp, const int* __restrict__ wp,
                         int N, int* par) {
    const int H = hp[0], W = wp[0];
    const int tpr = (W + 31) >> 5;
    const int ntiles = tpr * ((H + 31) >> 5);
    const int tidx = threadIdx.x;
    if (tidx >= 270) return;
    int li, lj;
    if (tidx < 96) {                       // rows {0,30,31}, all 32 cols
        const int r = tidx >> 5;
        li = (r == 0) ? 0 : 29 + r;
        lj = tidx & 31;
    } else {                               // rows 1..29, cols {0,1,2,29,30,31}
        const int u = tidx - 96;
        li = 1 + u / 6;
        const int c = u % 6;
        lj = (c < 3) ? c : 26 + c;
    }
    for (int tile = blockIdx.x; tile < ntiles; tile += gridDim.x) {
        const int i = ((tile / tpr) << 5) + li;
        const int j = ((tile % tpr) << 5) + lj;
        if (i >= H || j >= W) continue;
        const int t = i * W + j;
        const int p = pf[t];
        if (p != t) {
            const int pi = p / W, pj = p - pi * W;
            if (((pi ^ i) | (pj ^ j)) & ~31)          // parent in another tile
                uf_unite(t, p, par);
            continue;                                 // non-roots: no window edges
        }
        if (i > H - 2) continue;                      // all window rows need nh<=H-2
        int ru = -1, h0 = -1, h1 = -1;
        // dh=0 dedup'd rightward, cross-tile only (lj+d>31)
        for (int d = (lj >= 29 ? 32 - lj : 4); d <= 3; ++d) {
            if (j + d > W - 1) break;
            const int n = t + d;
            if (pf[n] != n) continue;
            const int pn = par[n];
            if (pn == h0 || pn == h1) continue;
            h1 = h0; h0 = pn;
            const int rv = find_ro(pn, par);
            if (ru == -1) ru = find_ro(t, par);
            if (rv != ru) ru = uf_link(ru, rv, par);
        }
        // dh in {1,2}
        for (int dh = 1; dh <= 2; ++dh) {
            const int nh = i + dh;
            if (nh > H - 2) break;
            const bool rowcross = (li + dh) > 31;
            for (int dw = -3; dw <= 2; ++dw) {
                const int nw = j + dw;
                if ((unsigned)nw > (unsigned)(W - 2)) continue;
                if (!rowcross && ((unsigned)(lj + dw) <= 31u)) continue;  // in-tile
                const int n = nh * W + nw;
                if (pf[n] != n) continue;
                const int pn = par[n];
                if (pn == h0 || pn == h1) continue;
                h1 = h0; h0 = pn;
                const int rv = find_ro(pn, par);
                if (ru == -1) ru = find_ro(t, par);
                if (rv != ru) ru = uf_link(ru, rv, par);
            }
        }
    }
}

// compress only the local-component roots; afterwards label(t) == par[par[t]]
__global__ void k_roots(const int* __restrict__ wlist, const int* __restrict__ wcount,
                        int* par) {
    const int n = *wcount;
    for (int k = blockIdx.x * blockDim.x + threadIdx.x; k < n;
         k += gridDim.x * blockDim.x) {
        const int r = wlist[k];
        par[r] = find_ro(r, par);   // plain store of final value (unions complete)
    }
}

__global__ void k_output(const float* __restrict__ ang,
                         const int* __restrict__ par, const int* __restrict__ pf,
                         const int* __restrict__ c3,
                         const int* __restrict__ hp, const int* __restrict__ wp,
                         int N, float* __restrict__ out) {
    int t = blockIdx.x * blockDim.x + threadIdx.x;
    if (t >= N) return;
    const int H = hp[0], W = wp[0];
    const int i = t / W, j = t - i * W;
    const float twopi = (float)(2.0 * PI_D);
    const int l = par[par[t]];
    float r0 = 0.0f, r1 = 0.0f;
    bool need = false;
    int l1 = l, l2 = l;
    if (j + 1 < W) { l1 = par[par[t + 1]]; need |= (l1 != l); }
    if (i + 1 < H) { l2 = par[par[t + W]]; need |= (l2 != l); }
    if (need) {
        auto c3v = [&](int x) {
            const int xi = x / W, xj = x - xi * W;
            const int xli = xi & 31, xlj = xj & 31;
            if (xli >= 3 && xli <= 28 && xlj >= 3 && xlj <= 28) return c3[x];
            int p = pf[x];
            p = pf[p];
            return pf[p];
        };
        const float ac = ang[c3v(t)];
        if (l1 != l) {
            float ad = fabsf(ac - ang[c3v(t + 1)]);
            r0 = fminf(ad, twopi - ad);
        }
        if (l2 != l) {
            float ad = fabsf(ac - ang[c3v(t + W)]);
            r1 = fminf(ad, twopi - ad);
        }
    }
    reinterpret_cast<float2*>(out)[t] = make_float2(r0, r1);
}

extern "C" void kernel_launch(void* const* d_in, const int* in_sizes, int n_in,
                              void* d_out, int out_size, void* d_ws, size_t ws_size,
                              hipStream_t stream) {
    const float* ang = (const float*)d_in[0];
    const int* hp  = (const int*)d_in[1];
    const int* wp  = (const int*)d_in[2];
    const int* tap = (const int*)d_in[3];
    const int N = in_sizes[0];

    int* base = (int*)d_ws;
    if (ws_size < ((size_t)4 * (size_t)N + 1) * sizeof(int) && N <= 262144) {
        void* p = nullptr;
        hipGetSymbolAddress(&p, HIP_SYMBOL(g_fb));   // host-side query; capture-safe
        base = (int*)p;
    }
    int* pf     = base;
    int* par    = base + N;
    int* c3     = base + 2 * N;
    int* wlist  = base + 3 * N;
    int* wcount = base + 4 * N;

    hipMemsetAsync(wcount, 0, sizeof(int), stream);   // ws is re-poisoned every call

    const int threads = 256;
    const int blocks = (N + threads - 1) / threads;
    k_local <<<256, 1024, 0, stream>>>(ang, hp, wp, tap, N, pf, par, c3, wlist, wcount);
    k_global<<<256, 320, 0, stream>>>(pf, hp, wp, N, par);
    k_roots <<<64, 256, 0, stream>>>(wlist, wcount, par);
    k_output<<<blocks, threads, 0, stream>>>(ang, par, pf, c3, hp, wp, N, (float*)d_out);
}